// Round 8
// baseline (19.227 us; speedup 1.0000x reference)
//
#include <hip/hip_runtime.h>

#define BATCH 32
#define DD 64
#define NN 8
#define SS 128
#define EPS_ 1e-6f
#define NTHREADS 1024
#define NK 15          // Krylov depth: u_0..u_15, deg-15 exp series (tail < 1e-6 at worst c~2.8)

typedef __attribute__((ext_vector_type(8))) short bf16x8;
typedef __attribute__((ext_vector_type(4))) float f32x4;

__device__ __forceinline__ unsigned short f2bf(float f) {
    unsigned u = __float_as_uint(f);
    unsigned r = u + 0x7FFFu + ((u >> 16) & 1u);   // round-to-nearest-even
    return (unsigned short)(r >> 16);
}
__device__ __forceinline__ float bf2f(unsigned short h) {
    return __uint_as_float(((unsigned)h) << 16);
}
// swizzled element index in a [64][64] bf16 matrix: 8-elem k-blocks contiguous,
// block index XORed with (row&7) so column reads spread across banks
__device__ __forceinline__ int SWZ(int r, int c) {
    return r * 64 + ((((c & ~7) ^ ((r & 7) << 3))) | (c & 7));
}
// A-fragment: 8 contiguous bf16 of row `row`, k-block k0 (multiple of 8)
__device__ __forceinline__ bf16x8 ldrow(const short* m, int row, int k0) {
    return *(const bf16x8*)&m[row * 64 + (k0 ^ ((row & 7) << 3))];
}
// B-fragment: 8 bf16 of column `col`, rows k0..k0+7
__device__ __forceinline__ bf16x8 ldcol(const short* m, int k0, int col) {
    bf16x8 v;
#pragma unroll
    for (int i = 0; i < 8; ++i) v[i] = m[SWZ(k0 + i, col)];
    return v;
}

#define MFMA(a, b, c) __builtin_amdgcn_mfma_f32_16x16x32_bf16((a), (b), (c), 0, 0, 0)

__launch_bounds__(NTHREADS)
__global__ void htg_kernel(const float* __restrict__ z0,
                           const float* __restrict__ time_steps,
                           const float* __restrict__ k_coeffs,
                           const float* __restrict__ r_coeffs,
                           const float* __restrict__ alpha_p,
                           const float* __restrict__ beta_p,
                           const float* __restrict__ K_bases,
                           const float* __restrict__ R_bases,
                           float* __restrict__ out,
                           int interleaved)
{
    __shared__ float bufA[DD * DD];      // Ksum fp32 (elem-XOR)  -> X2 fp32 (plain)
    __shared__ float bufB[DD * DD];      // rh/rl split-bf16 R    -> x2h/x2l split-bf16 X2
    __shared__ float bufD[DD * DD];      // xh/xl split-bf16 X    -> X4 fp32 (plain)
    __shared__ float us[NK + 1][DD];     // Krylov vectors u_k = X^k z0

    short* rh  = (short*)bufB;  short* rl  = rh  + DD * DD;
    short* x2h = rh;            short* x2l = rl;            // reuse after MM1
    short* xh  = (short*)bufD;  short* xl  = xh  + DD * DD;
    float* X2f = bufA;
    float* X4f = bufD;

    const int tid = threadIdx.x;
    const int b   = blockIdx.x;          // batch
    const int wv  = tid >> 6;            // wave 0..15 -> 16x16 tile (tr, tc)
    const int l   = tid & 63;
    const int tr  = wv >> 2, tc = wv & 3;
    const int q   = l >> 4;              // k-subgroup 0..3
    const int cl  = l & 15;
    const int mi  = tid >> 4, mh = tid & 15;   // matvec row / k-chunk

    const float alpha = alpha_p[b];
    const float beta  = beta_p[b];
    const float dt    = time_steps[0];   // uniform grid
    float kc[NN], rc[NN];
#pragma unroll
    for (int n = 0; n < NN; ++n) {
        kc[n] = k_coeffs[b * NN + n];
        rc[n] = r_coeffs[b * NN + n];
    }
    if (tid < DD) us[0][tid] = z0[b * DD + tid];

    // ---- Phase A: Ksum fp32 (elem-XOR) -> bufA; Rsum split-bf16 (SWZ) -> rh/rl ----
    {
        const int i  = tid >> 4;
        const int j0 = (tid & 15) * 4;
        const int e4 = i * DD + j0;
        float4 ks = make_float4(0.f, 0.f, 0.f, 0.f);
        float4 rs = make_float4(0.f, 0.f, 0.f, 0.f);
#pragma unroll
        for (int n = 0; n < NN; ++n) {
            float4 kb = *(const float4*)&K_bases[n * DD * DD + e4];
            float4 rb = *(const float4*)&R_bases[n * DD * DD + e4];
            ks.x = fmaf(kc[n], kb.x, ks.x); ks.y = fmaf(kc[n], kb.y, ks.y);
            ks.z = fmaf(kc[n], kb.z, ks.z); ks.w = fmaf(kc[n], kb.w, ks.w);
            rs.x = fmaf(rc[n], rb.x, rs.x); rs.y = fmaf(rc[n], rb.y, rs.y);
            rs.z = fmaf(rc[n], rb.z, rs.z); rs.w = fmaf(rc[n], rb.w, rs.w);
        }
        const int c = i & 31;
        bufA[i * DD + ((j0 + 0) ^ c)] = ks.x;
        bufA[i * DD + ((j0 + 1) ^ c)] = ks.y;
        bufA[i * DD + ((j0 + 2) ^ c)] = ks.z;
        bufA[i * DD + ((j0 + 3) ^ c)] = ks.w;
        float rv[4] = {rs.x, rs.y, rs.z, rs.w};
#pragma unroll
        for (int t = 0; t < 4; ++t) {
            unsigned short h  = f2bf(rv[t]);
            unsigned short lo = f2bf(rv[t] - bf2f(h));
            const int a = SWZ(i, j0 + t);
            rh[a] = (short)h; rl[a] = (short)lo;
        }
    }
    __syncthreads();

    // ---- MM1 (MFMA): RtR = R^T R (split); X = dt*(alpha*(K-K^T) - beta*RtR) + eps*I
    //      X stored split-bf16 only -> xh/xl (bufD fresh, no WAR) ----
    {
        f32x4 accR = {0.f, 0.f, 0.f, 0.f};
        const int colA = 16 * tr + cl;   // A = R^T: row of A == column of R
        const int colB = 16 * tc + cl;
#pragma unroll
        for (int hK = 0; hK < 2; ++hK) {
            const int k0 = 32 * hK + 8 * q;
            bf16x8 aH = ldcol(rh, k0, colA), aL = ldcol(rl, k0, colA);
            bf16x8 bH = ldcol(rh, k0, colB), bL = ldcol(rl, k0, colB);
            accR = MFMA(aH, bH, accR);
            accR = MFMA(aH, bL, accR);
            accR = MFMA(aL, bH, accR);
        }
#pragma unroll
        for (int r = 0; r < 4; ++r) {
            const int i = 16 * tr + 4 * q + r;
            const int j = 16 * tc + cl;
            const float kij = bufA[i * DD + (j ^ (i & 31))];
            const float kji = bufA[j * DD + (i ^ (j & 31))];
            float x = dt * (alpha * (kij - kji) - beta * accR[r]);
            if (i == j) x += EPS_;
            unsigned short h  = f2bf(x);
            unsigned short lo = f2bf(x - bf2f(h));
            const int a = SWZ(i, j);
            xh[a] = (short)h; xl[a] = (short)lo;
        }
    }
    __syncthreads();

    const int rowA = 16 * tr + cl;
    const int colB = 16 * tc + cl;

    // ---- P2: X2 = X*X (MFMA split) -> X2f (bufA) + x2h/x2l (bufB);  u1 = X*u0 (VALU, split X) ----
    {
        f32x4 acc2 = {0.f, 0.f, 0.f, 0.f};
#pragma unroll
        for (int hK = 0; hK < 2; ++hK) {
            const int k0 = 32 * hK + 8 * q;
            bf16x8 aH = ldrow(xh, rowA, k0), aL = ldrow(xl, rowA, k0);
            bf16x8 bH = ldcol(xh, k0, colB), bL = ldcol(xl, k0, colB);
            acc2 = MFMA(aH, bH, acc2);
            acc2 = MFMA(aH, bL, acc2);
            acc2 = MFMA(aL, bH, acc2);
        }
        // u1: row mi, cols 4mh..4mh+3 of X from split-bf16 (contiguous within 8-block)
        {
            const int c0  = 4 * mh;
            const int idx = mi * DD + (((c0 & ~7) ^ ((mi & 7) << 3)) | (c0 & 7));
            const ushort* uh = (const ushort*)xh;
            const ushort* ul = (const ushort*)xl;
            ushort4 h4 = *(const ushort4*)&uh[idx];
            ushort4 l4 = *(const ushort4*)&ul[idx];
            float4 v = *(const float4*)&us[0][c0];
            float p;
            p = (bf2f(h4.x) + bf2f(l4.x)) * v.x;
            p = fmaf(bf2f(h4.y) + bf2f(l4.y), v.y, p);
            p = fmaf(bf2f(h4.z) + bf2f(l4.z), v.z, p);
            p = fmaf(bf2f(h4.w) + bf2f(l4.w), v.w, p);
            p += __shfl_xor(p, 1, 16);
            p += __shfl_xor(p, 2, 16);
            p += __shfl_xor(p, 4, 16);
            p += __shfl_xor(p, 8, 16);
            if (mh == 0) us[1][mi] = p;
        }
        // write X2: fp32 plain (bufA; Ksum dead) + split (bufB; rh/rl dead)
#pragma unroll
        for (int r = 0; r < 4; ++r) {
            const int i = 16 * tr + 4 * q + r;
            const int j = 16 * tc + cl;
            X2f[i * DD + j] = acc2[r];
            unsigned short h  = f2bf(acc2[r]);
            unsigned short lo = f2bf(acc2[r] - bf2f(h));
            const int a = SWZ(i, j);
            x2h[a] = (short)h; x2l[a] = (short)lo;
        }
    }
    __syncthreads();

    // ---- P3: X4 = X2*X2 (MFMA split) -> X4f (bufD; xh/xl dead);  u2,u3 = X2*(u0,u1) ----
    {
        f32x4 acc4 = {0.f, 0.f, 0.f, 0.f};
#pragma unroll
        for (int hK = 0; hK < 2; ++hK) {
            const int k0 = 32 * hK + 8 * q;
            bf16x8 aH = ldrow(x2h, rowA, k0), aL = ldrow(x2l, rowA, k0);
            bf16x8 bH = ldcol(x2h, k0, colB), bL = ldcol(x2l, k0, colB);
            acc4 = MFMA(aH, bH, acc4);
            acc4 = MFMA(aH, bL, acc4);
            acc4 = MFMA(aL, bH, acc4);
        }
        const float4 m2 = *(const float4*)&X2f[mi * DD + 4 * mh];
#pragma unroll
        for (int v = 0; v < 2; ++v) {
            float4 vv = *(const float4*)&us[v][4 * mh];
            float p = fmaf(m2.x, vv.x, fmaf(m2.y, vv.y, fmaf(m2.z, vv.z, m2.w * vv.w)));
            p += __shfl_xor(p, 1, 16);
            p += __shfl_xor(p, 2, 16);
            p += __shfl_xor(p, 4, 16);
            p += __shfl_xor(p, 8, 16);
            if (mh == 0) us[2 + v][mi] = p;
        }
#pragma unroll
        for (int r = 0; r < 4; ++r) {
            const int i = 16 * tr + 4 * q + r;
            const int j = 16 * tc + cl;
            X4f[i * DD + j] = acc4[r];
        }
    }
    __syncthreads();

    // ---- P4/P5/P6: u[4g+4..4g+7] = X4 * u[4g..4g+3], g = 0,1,2  (sources strictly earlier) ----
    {
        const float4 m4 = *(const float4*)&X4f[mi * DD + 4 * mh];
        for (int grp = 0; grp < 3; ++grp) {
#pragma unroll
            for (int v = 0; v < 4; ++v) {
                float4 vv = *(const float4*)&us[4 * grp + v][4 * mh];
                float p = fmaf(m4.x, vv.x, fmaf(m4.y, vv.y, fmaf(m4.z, vv.z, m4.w * vv.w)));
                p += __shfl_xor(p, 1, 16);
                p += __shfl_xor(p, 2, 16);
                p += __shfl_xor(p, 4, 16);
                p += __shfl_xor(p, 8, 16);
                if (mh == 0) us[4 * grp + 4 + v][mi] = p;
            }
            __syncthreads();
        }
    }

    // ---- Output: z_s[i] = sum_k (s+1)^k/k! * u_k[i], all 128 steps in parallel ----
    {
        const int i  = tid & 63;
        const int sb = tid >> 6;         // 0..15
        float uk[NK + 1];
#pragma unroll
        for (int k = 0; k <= NK; ++k) uk[k] = us[k][i];
#pragma unroll
        for (int r = 0; r < 8; ++r) {
            const int s = sb + 16 * r;
            const float t = (float)(s + 1);
            float f = 1.f;
            float acc = uk[0];
#pragma unroll
            for (int k = 1; k <= NK; ++k) {
                f *= t * (1.f / (float)k);       // f = t^k / k!
                acc = fmaf(f, uk[k], acc);
            }
            const size_t oi = ((size_t)(b * SS + s)) * DD + i;
            if (interleaved) ((float2*)out)[oi] = make_float2(acc, 0.f);
            else             out[oi] = acc;
        }
    }
}

extern "C" void kernel_launch(void* const* d_in, const int* in_sizes, int n_in,
                              void* d_out, int out_size, void* d_ws, size_t ws_size,
                              hipStream_t stream) {
    const float* z0         = (const float*)d_in[0];
    const float* time_steps = (const float*)d_in[1];
    const float* k_coeffs   = (const float*)d_in[2];
    const float* r_coeffs   = (const float*)d_in[3];
    const float* alpha      = (const float*)d_in[4];
    const float* beta       = (const float*)d_in[5];
    const float* K_bases    = (const float*)d_in[6];
    const float* R_bases    = (const float*)d_in[7];
    float* out = (float*)d_out;

    const int n_z = BATCH * SS * DD;
    const int interleaved = (out_size >= 2 * n_z) ? 1 : 0;

    htg_kernel<<<dim3(BATCH), dim3(NTHREADS), 0, stream>>>(
        z0, time_steps, k_coeffs, r_coeffs, alpha, beta, K_bases, R_bases,
        out, interleaved);
}

// Round 9
// 17.027 us; speedup vs baseline: 1.1292x; 1.1292x over previous
//
#include <hip/hip_runtime.h>

#define BATCH 32
#define DD 64
#define NN 8
#define SS 128
#define EPS_ 1e-6f
#define NTHREADS 1024
#define NK 15          // Krylov depth: u_0..u_15; tail at worst c~2.8: 2.8^16/16! ~ 7e-7
#define SX 65          // bX row stride in floats (odd mod 32 -> bank-spread rows)

typedef __attribute__((ext_vector_type(8))) short bf16x8;
typedef __attribute__((ext_vector_type(4))) float f32x4;

__device__ __forceinline__ unsigned short f2bf(float f) {
    unsigned u = __float_as_uint(f);
    unsigned r = u + 0x7FFFu + ((u >> 16) & 1u);   // round-to-nearest-even
    return (unsigned short)(r >> 16);
}
__device__ __forceinline__ float bf2f(unsigned short h) {
    return __uint_as_float(((unsigned)h) << 16);
}
// swizzled element index in a [64][64] bf16 matrix: 8-elem k-blocks contiguous,
// block index XORed with (row&7) so cross-row access spreads across banks
__device__ __forceinline__ int SWZ(int r, int c) {
    return r * 64 + ((((c & ~7) ^ ((r & 7) << 3))) | (c & 7));
}
// 8 contiguous bf16 of row `row`, k-block k0 (multiple of 8)
__device__ __forceinline__ bf16x8 ldrow(const short* m, int row, int k0) {
    return *(const bf16x8*)&m[row * 64 + (k0 ^ ((row & 7) << 3))];
}

#define MFMA(a, b, c) __builtin_amdgcn_mfma_f32_16x16x32_bf16((a), (b), (c), 0, 0, 0)

__launch_bounds__(NTHREADS)
__global__ void htg_kernel(const float* __restrict__ z0,
                           const float* __restrict__ time_steps,
                           const float* __restrict__ k_coeffs,
                           const float* __restrict__ r_coeffs,
                           const float* __restrict__ alpha_p,
                           const float* __restrict__ beta_p,
                           const float* __restrict__ K_bases,
                           const float* __restrict__ R_bases,
                           float* __restrict__ out,
                           int interleaved)
{
    __shared__ float bK[DD * DD];        // Ksum fp32, elem-XOR layout
    __shared__ short rtH[DD * DD];       // Rsum^T bf16 high (SWZ rows)
    __shared__ short rtL[DD * DD];       // Rsum^T bf16 low residual
    __shared__ float bX[DD * SX];        // X fp32, stride-65 rows
    __shared__ float us[NK + 1][DD];     // Krylov vectors u_k = X^k z0
    __shared__ float ub[DD];             // current u (chain broadcast buffer)

    const int tid = threadIdx.x;
    const int b   = blockIdx.x;          // batch
    const int wv  = tid >> 6;            // wave 0..15 -> 16x16 tile (tr, tc)
    const int l   = tid & 63;
    const int tr  = wv >> 2, tc = wv & 3;
    const int q   = l >> 4;              // k-subgroup 0..3
    const int cl  = l & 15;

    const float alpha = alpha_p[b];
    const float beta  = beta_p[b];
    const float dt    = time_steps[0];   // uniform grid
    float kc[NN], rc[NN];
#pragma unroll
    for (int n = 0; n < NN; ++n) {
        kc[n] = k_coeffs[b * NN + n];
        rc[n] = r_coeffs[b * NN + n];
    }
    float zv = 0.f;
    if (wv == 0) zv = z0[b * DD + l];    // early; latency hides under Phase A

    // ---- Phase A: Ksum fp32 (elem-XOR) -> bK; Rsum^T split-bf16 (SWZ) -> rtH/rtL ----
    {
        const int i  = tid >> 4;
        const int j0 = (tid & 15) * 4;
        const int e4 = i * DD + j0;
        float4 ks = make_float4(0.f, 0.f, 0.f, 0.f);
        float4 rs = make_float4(0.f, 0.f, 0.f, 0.f);
#pragma unroll
        for (int n = 0; n < NN; ++n) {
            float4 kb = *(const float4*)&K_bases[n * DD * DD + e4];
            float4 rb = *(const float4*)&R_bases[n * DD * DD + e4];
            ks.x = fmaf(kc[n], kb.x, ks.x); ks.y = fmaf(kc[n], kb.y, ks.y);
            ks.z = fmaf(kc[n], kb.z, ks.z); ks.w = fmaf(kc[n], kb.w, ks.w);
            rs.x = fmaf(rc[n], rb.x, rs.x); rs.y = fmaf(rc[n], rb.y, rs.y);
            rs.z = fmaf(rc[n], rb.z, rs.z); rs.w = fmaf(rc[n], rb.w, rs.w);
        }
        const int c = i & 31;
        bK[i * DD + ((j0 + 0) ^ c)] = ks.x;
        bK[i * DD + ((j0 + 1) ^ c)] = ks.y;
        bK[i * DD + ((j0 + 2) ^ c)] = ks.z;
        bK[i * DD + ((j0 + 3) ^ c)] = ks.w;
        // transposed store: value (i, j0+t) -> RT[j0+t][i]
        float rv[4] = {rs.x, rs.y, rs.z, rs.w};
#pragma unroll
        for (int t = 0; t < 4; ++t) {
            unsigned short h  = f2bf(rv[t]);
            unsigned short lo = f2bf(rv[t] - bf2f(h));
            const int a = SWZ(j0 + t, i);
            rtH[a] = (short)h; rtL[a] = (short)lo;
        }
    }
    __syncthreads();

    // ---- MM1 (MFMA): RtR[i][j] = sum_k RT[i][k]*RT[j][k]; all fragments b128 row reads.
    //      X = dt*(alpha*(K-K^T) - beta*RtR) + eps*I -> bX fp32 (stride 65) ----
    {
        f32x4 accR = {0.f, 0.f, 0.f, 0.f};
        const int rowA = 16 * tr + cl;
        const int rowB = 16 * tc + cl;   // B[k][j] = RT[j][k] -> row j of RT
#pragma unroll
        for (int hK = 0; hK < 2; ++hK) {
            const int k0 = 32 * hK + 8 * q;
            bf16x8 aH = ldrow(rtH, rowA, k0), aL = ldrow(rtL, rowA, k0);
            bf16x8 bH = ldrow(rtH, rowB, k0), bL = ldrow(rtL, rowB, k0);
            accR = MFMA(aH, bH, accR);
            accR = MFMA(aH, bL, accR);
            accR = MFMA(aL, bH, accR);
        }
#pragma unroll
        for (int r = 0; r < 4; ++r) {
            const int i = 16 * tr + 4 * q + r;
            const int j = 16 * tc + cl;
            const float kij = bK[i * DD + (j ^ (i & 31))];
            const float kji = bK[j * DD + (i ^ (j & 31))];
            float x = dt * (alpha * (kij - kji) - beta * accR[r]);
            if (i == j) x += EPS_;
            bX[i * SX + j] = x;
        }
    }
    __syncthreads();

    // ---- Chain (wave 0 only, barrier-free): u_k = X*u_{k-1}, k=1..NK ----
    if (wv == 0) {
        float xr[DD];                    // row l of X in registers (compile-time indexed)
#pragma unroll
        for (int c = 0; c < DD; c += 4) {
            float4 t4 = *(const float4*)&bX[l * SX + c];
            xr[c + 0] = t4.x; xr[c + 1] = t4.y; xr[c + 2] = t4.z; xr[c + 3] = t4.w;
        }
        us[0][l] = zv;
        ub[l]    = zv;
        asm volatile("s_waitcnt lgkmcnt(0)" ::: "memory");
        for (int k = 1; k <= NK; ++k) {
            float a0 = 0.f, a1 = 0.f, a2 = 0.f, a3 = 0.f;
#pragma unroll
            for (int c = 0; c < DD; c += 16) {
                float4 v0 = *(const float4*)&ub[c + 0];
                float4 v1 = *(const float4*)&ub[c + 4];
                float4 v2 = *(const float4*)&ub[c + 8];
                float4 v3 = *(const float4*)&ub[c + 12];
                a0 = fmaf(xr[c + 0], v0.x, a0); a0 = fmaf(xr[c + 1], v0.y, a0);
                a0 = fmaf(xr[c + 2], v0.z, a0); a0 = fmaf(xr[c + 3], v0.w, a0);
                a1 = fmaf(xr[c + 4], v1.x, a1); a1 = fmaf(xr[c + 5], v1.y, a1);
                a1 = fmaf(xr[c + 6], v1.z, a1); a1 = fmaf(xr[c + 7], v1.w, a1);
                a2 = fmaf(xr[c + 8], v2.x, a2); a2 = fmaf(xr[c + 9], v2.y, a2);
                a2 = fmaf(xr[c + 10], v2.z, a2); a2 = fmaf(xr[c + 11], v2.w, a2);
                a3 = fmaf(xr[c + 12], v3.x, a3); a3 = fmaf(xr[c + 13], v3.y, a3);
                a3 = fmaf(xr[c + 14], v3.z, a3); a3 = fmaf(xr[c + 15], v3.w, a3);
            }
            const float un = (a0 + a1) + (a2 + a3);
            ub[l]    = un;               // data-dep ensures reads consumed before write
            us[k][l] = un;
            asm volatile("s_waitcnt lgkmcnt(0)" ::: "memory");  // write visible before next reads
        }
    }
    __syncthreads();

    // ---- Output: z_s[i] = sum_k (s+1)^k/k! * u_k[i], all 128 steps in parallel ----
    {
        const int i  = tid & 63;
        const int sb = tid >> 6;         // 0..15
        float uk[NK + 1];
#pragma unroll
        for (int k = 0; k <= NK; ++k) uk[k] = us[k][i];
#pragma unroll
        for (int r = 0; r < 8; ++r) {
            const int s = sb + 16 * r;
            const float t = (float)(s + 1);
            float f = 1.f;
            float acc = uk[0];
#pragma unroll
            for (int k = 1; k <= NK; ++k) {
                f *= t * (1.f / (float)k);       // f = t^k / k!
                acc = fmaf(f, uk[k], acc);
            }
            const size_t oi = ((size_t)(b * SS + s)) * DD + i;
            if (interleaved) ((float2*)out)[oi] = make_float2(acc, 0.f);
            else             out[oi] = acc;
        }
    }
}

extern "C" void kernel_launch(void* const* d_in, const int* in_sizes, int n_in,
                              void* d_out, int out_size, void* d_ws, size_t ws_size,
                              hipStream_t stream) {
    const float* z0         = (const float*)d_in[0];
    const float* time_steps = (const float*)d_in[1];
    const float* k_coeffs   = (const float*)d_in[2];
    const float* r_coeffs   = (const float*)d_in[3];
    const float* alpha      = (const float*)d_in[4];
    const float* beta       = (const float*)d_in[5];
    const float* K_bases    = (const float*)d_in[6];
    const float* R_bases    = (const float*)d_in[7];
    float* out = (float*)d_out;

    const int n_z = BATCH * SS * DD;
    const int interleaved = (out_size >= 2 * n_z) ? 1 : 0;

    htg_kernel<<<dim3(BATCH), dim3(NTHREADS), 0, stream>>>(
        z0, time_steps, k_coeffs, r_coeffs, alpha, beta, K_bases, R_bases,
        out, interleaved);
}